// Round 7
// baseline (261.942 us; speedup 1.0000x reference)
//
#include <hip/hip_runtime.h>

// KNN top-16: B=4, N=M=8192, C=3.  (GOLD METRIC LOCKED by R17, absmax=0:
//   norms = (x²+z²)+y² [hsum, plain]; cross = fma(z,z',fma(y,y',x*x'));
//   d2 = max((q2+r2) - 2*cross, 0); stable (d2,idx) ascending; 0-based.)
// R20 (re-anchored R25 @227us): u64 keys, persistent candidate buffer,
//   batched sort16+bitonic-merge compact, shfl tree merge, (128,4).
//   Matrix lesson R21-R24: (128,4)+float4-staging is the only fast point;
//   all "fixes" of its hidden spills/conflicts added exposed stall.
// R26: packed-f32 metric (v_pk_mul/fma/add_f32 — two bit-identical IEEE
//   f32 ops per instruction, CDNA2+). Tile goes SoA (tx/ty/tz/tw[512]) so
//   ds_read_b128 yields 4 consecutive points per coord, pre-paired for pk.
//   j^h block swizzle keeps SoA reads conflict-free at ZERO pad: LDS stays
//   20480B (same occupancy); staging writes drop 32-way -> 8-way conflict.
//   Partition becomes contiguous (thread h owns locs [h*64,(h+1)*64)) —
//   screen-T induction and key-merge are partition-independent.
//   Everything else byte-identical to the 227us kernel.

#define TPB 128
#define QPB 16   // queries per block
#define SPL 8    // threads per query
#define KK 16
#define TILE_PTS 512
#define CAP 16   // LDS candidate slots per thread
#define TRIG 8   // compaction trigger (checked every 8; 7+8 <= 15 < CAP)

typedef unsigned long long u64k;
typedef float f32x2 __attribute__((ext_vector_type(2)));

__device__ __forceinline__ f32x2 pk_mul(f32x2 a, f32x2 b) {
  f32x2 d;
  asm("v_pk_mul_f32 %0, %1, %2" : "=v"(d) : "v"(a), "v"(b));
  return d;
}
__device__ __forceinline__ f32x2 pk_fma(f32x2 a, f32x2 b, f32x2 c) {
  f32x2 d;
  asm("v_pk_fma_f32 %0, %1, %2, %3" : "=v"(d) : "v"(a), "v"(b), "v"(c));
  return d;
}
__device__ __forceinline__ f32x2 pk_add(f32x2 a, f32x2 b) {
  f32x2 d;
  asm("v_pk_add_f32 %0, %1, %2" : "=v"(d) : "v"(a), "v"(b));
  return d;
}

#define CE(x, i, j)                                   \
  {                                                   \
    u64k ki_ = x[i], kj_ = x[j];                      \
    bool c_ = kj_ < ki_;                              \
    x[i] = c_ ? kj_ : ki_;                            \
    x[j] = c_ ? ki_ : kj_;                            \
  }

// Batcher odd-even mergesort, 16 elements, 63 comparators.
__device__ __forceinline__ void sort16(u64k x[KK]) {
  CE(x,0,1) CE(x,2,3) CE(x,4,5) CE(x,6,7) CE(x,8,9) CE(x,10,11) CE(x,12,13) CE(x,14,15)
  CE(x,0,2) CE(x,1,3) CE(x,4,6) CE(x,5,7) CE(x,8,10) CE(x,9,11) CE(x,12,14) CE(x,13,15)
  CE(x,1,2) CE(x,5,6) CE(x,9,10) CE(x,13,14)
  CE(x,0,4) CE(x,1,5) CE(x,2,6) CE(x,3,7) CE(x,8,12) CE(x,9,13) CE(x,10,14) CE(x,11,15)
  CE(x,2,4) CE(x,3,5) CE(x,10,12) CE(x,11,13)
  CE(x,1,2) CE(x,3,4) CE(x,5,6) CE(x,9,10) CE(x,11,12) CE(x,13,14)
  CE(x,0,8) CE(x,1,9) CE(x,2,10) CE(x,3,11) CE(x,4,12) CE(x,5,13) CE(x,6,14) CE(x,7,15)
  CE(x,4,8) CE(x,5,9) CE(x,6,10) CE(x,7,11)
  CE(x,2,4) CE(x,3,5) CE(x,6,8) CE(x,7,9) CE(x,10,12) CE(x,11,13)
  CE(x,1,2) CE(x,3,4) CE(x,5,6) CE(x,7,8) CE(x,9,10) CE(x,11,12) CE(x,13,14)
}

// a asc, e asc -> a = 16 smallest of (a ∪ e), ascending.
__device__ __forceinline__ void mergeTop16(u64k a[KK], u64k e[KK]) {
#pragma unroll
  for (int i = 0; i < KK; ++i) {
    u64k bv = e[KK - 1 - i];
    if (bv < a[i]) a[i] = bv;
  }
  // bitonic clean (distances 8,4,2,1)
  CE(a,0,8) CE(a,1,9) CE(a,2,10) CE(a,3,11) CE(a,4,12) CE(a,5,13) CE(a,6,14) CE(a,7,15)
  CE(a,0,4) CE(a,1,5) CE(a,2,6) CE(a,3,7) CE(a,8,12) CE(a,9,13) CE(a,10,14) CE(a,11,15)
  CE(a,0,2) CE(a,1,3) CE(a,4,6) CE(a,5,7) CE(a,8,10) CE(a,9,11) CE(a,12,14) CE(a,13,15)
  CE(a,0,1) CE(a,2,3) CE(a,4,5) CE(a,6,7) CE(a,8,9) CE(a,10,11) CE(a,12,13) CE(a,14,15)
}

__global__ __launch_bounds__(TPB, 4) void knn_topk_kernel(
    const float* __restrict__ ref, const float* __restrict__ query,
    float* __restrict__ dout, float* __restrict__ iout, int N, int M) {
#pragma clang fp contract(off)
  // SoA tile, j^h block-swizzled: coord[h*64 + (j^h)*4 + c] holds point
  // loc = h*64 + j*4 + c.  Reads: 8 h-groups hit banks 4*(j^h&7) .. +3 —
  // all 32 banks exactly once, conflict-free, zero pad.
  __shared__ float tx[TILE_PTS], ty[TILE_PTS], tz[TILE_PTS], tw[TILE_PTS];
  __shared__ unsigned int sd[CAP * TPB];    // 8 KB: candidate d2bits (clamped)
  __shared__ unsigned short sg[CAP * TPB];  // 4 KB: candidate global idx

  float4* tx4 = (float4*)tx;
  float4* ty4 = (float4*)ty;
  float4* tz4 = (float4*)tz;
  float4* tw4 = (float4*)tw;

  const int tid = threadIdx.x;
  const int h = tid & (SPL - 1);
  const int qid = blockIdx.x * QPB + (tid >> 3);
  const int b = qid / M;

  const float* qp = query + (size_t)qid * 3;
  const float qx = qp[0], qy = qp[1], qz = qp[2];
  // HSUM norm (SSE2 movehl reduction of [x2,y2,z2,0]): (x2 + z2) + y2
  const float q2 = (qx * qx + qz * qz) + qy * qy;
  const f32x2 qxx = {qx, qx}, qyy = {qy, qy}, qzz = {qz, qz};
  const f32x2 q22 = {q2, q2}, n22 = {-2.0f, -2.0f};

  u64k kl[KK];  // sorted ascending (d2bits<<32 | gidx) = lex (d2, idx)
  float T;      // shared screen threshold (min of 8 threads' 16th)
  int cnt = 0;

  const float* refb = ref + (size_t)b * N * 3;

  // Batched compact: pull pending (d2bits,gidx) pairs, sort, merge into kl.
  auto compact = [&]() {
    u64k e[KK];
#pragma unroll
    for (int s = 0; s < KK; ++s) {
      unsigned int db = sd[s * TPB + tid];
      unsigned int gi = sg[s * TPB + tid];
      u64k key = ((u64k)db << 32) | gi;
      e[s] = (s < cnt) ? key : ~0ull;  // pads sort to the top, fall out
    }
    sort16(e);
    mergeTop16(kl, e);
    cnt = 0;
    float a15 = __uint_as_float((unsigned)(kl[KK - 1] >> 32));
    float m = fminf(a15, __shfl_xor(a15, 1));
    m = fminf(m, __shfl_xor(m, 2));
    T = fminf(m, __shfl_xor(m, 4));
  };

  // Packed metric for block j of this thread's subset: 4 consecutive points
  // loc = h*64 + j*4 + {0..3}.  Exact locked chain per lane-half:
  // cr = fma(qz,z,fma(qy,y,qx*x)); s2 = q2+r2; d2 = fma(-2,cr,s2).
  auto evalg = [&](int j, f32x2& d01, f32x2& d23) {
    int ridx = (h << 4) + (j ^ h);
    float4 xs = tx4[ridx];
    float4 ys = ty4[ridx];
    float4 zs = tz4[ridx];
    float4 ws = tw4[ridx];
    f32x2 x01 = {xs.x, xs.y}, x23 = {xs.z, xs.w};
    f32x2 y01 = {ys.x, ys.y}, y23 = {ys.z, ys.w};
    f32x2 z01 = {zs.x, zs.y}, z23 = {zs.z, zs.w};
    f32x2 w01 = {ws.x, ws.y}, w23 = {ws.z, ws.w};
    f32x2 cr01 = pk_mul(qxx, x01);
    cr01 = pk_fma(qyy, y01, cr01);
    cr01 = pk_fma(qzz, z01, cr01);
    f32x2 s01 = pk_add(q22, w01);
    d01 = pk_fma(n22, cr01, s01);
    f32x2 cr23 = pk_mul(qxx, x23);
    cr23 = pk_fma(qyy, y23, cr23);
    cr23 = pk_fma(qzz, z23, cr23);
    f32x2 s23 = pk_add(q22, w23);
    d23 = pk_fma(n22, cr23, s23);
  };

  auto app = [&](float d2, int gi) {
    if (d2 <= T) {  // conservative shared screen (<= keeps exact ties)
      float d2c = d2 < 0.f ? 0.f : d2;
      sd[cnt * TPB + tid] = __float_as_uint(d2c);
      sg[cnt * TPB + tid] = (unsigned short)gi;
      cnt++;
    }
  };

  const int ntiles = N / TILE_PTS;
  for (int t = 0; t < ntiles; ++t) {
    __syncthreads();
    {
      // Stage 4 points/thread via 3 float4 loads (48 B, 16B-aligned) —
      // identical global pattern to the 227us kernel; transpose to SoA in
      // registers; swizzled float4 writes (8-way conflict vs old 32-way).
      int pl = tid * 4;
      const float4* rp =
          (const float4*)(refb + (size_t)(t * TILE_PTS + pl) * 3);
      float4 f0 = rp[0], f1 = rp[1], f2 = rp[2];
      float x0 = f0.x, y0 = f0.y, z0 = f0.z;
      float x1 = f0.w, y1 = f1.x, z1 = f1.y;
      float x2 = f1.z, y2 = f1.w, z2 = f2.x;
      float x3 = f2.y, y3 = f2.z, z3 = f2.w;
      int widx = ((tid >> 4) << 4) + ((tid & 15) ^ (tid >> 4));
      tx4[widx] = make_float4(x0, x1, x2, x3);
      ty4[widx] = make_float4(y0, y1, y2, y3);
      tz4[widx] = make_float4(z0, z1, z2, z3);
      tw4[widx] = make_float4((x0 * x0 + z0 * z0) + y0 * y0,
                              (x1 * x1 + z1 * z1) + y1 * y1,
                              (x2 * x2 + z2 * z2) + y2 * y2,
                              (x3 * x3 + z3 * z3) + y3 * y3);
    }
    __syncthreads();
    const int tbase = t * TILE_PTS;
    int j0 = 0;
    if (t == 0) {
      // Fill: this thread's first 16 points (j=0..3), exact chain, one sort.
#pragma unroll
      for (int j = 0; j < 4; ++j) {
        f32x2 d01, d23;
        evalg(j, d01, d23);
        int gb = (h << 6) + (j << 2);
        float v0 = d01.x < 0.f ? 0.f : d01.x;
        float v1 = d01.y < 0.f ? 0.f : d01.y;
        float v2 = d23.x < 0.f ? 0.f : d23.x;
        float v3 = d23.y < 0.f ? 0.f : d23.y;
        kl[j * 4 + 0] = ((u64k)__float_as_uint(v0) << 32) | (unsigned)(gb + 0);
        kl[j * 4 + 1] = ((u64k)__float_as_uint(v1) << 32) | (unsigned)(gb + 1);
        kl[j * 4 + 2] = ((u64k)__float_as_uint(v2) << 32) | (unsigned)(gb + 2);
        kl[j * 4 + 3] = ((u64k)__float_as_uint(v3) << 32) | (unsigned)(gb + 3);
      }
      sort16(kl);
      float a15 = __uint_as_float((unsigned)(kl[KK - 1] >> 32));
      float m = fminf(a15, __shfl_xor(a15, 1));
      m = fminf(m, __shfl_xor(m, 2));
      T = fminf(m, __shfl_xor(m, 4));
      j0 = 4;
    }
    for (int j = j0; j < TILE_PTS / SPL / 4; j += 2) {
      {
        f32x2 d01, d23;
        evalg(j, d01, d23);
        int gb = tbase + (h << 6) + (j << 2);
        app(d01.x, gb + 0);
        app(d01.y, gb + 1);
        app(d23.x, gb + 2);
        app(d23.y, gb + 3);
      }
      {
        f32x2 d01, d23;
        evalg(j + 1, d01, d23);
        int gb = tbase + (h << 6) + ((j + 1) << 2);
        app(d01.x, gb + 0);
        app(d01.y, gb + 1);
        app(d23.x, gb + 2);
        app(d23.y, gb + 3);
      }
      if (__any(cnt >= TRIG)) compact();  // wave-synchronized
    }
    // no forced per-tile compact: entries carry global idx + exact d2bits
  }
  if (__any(cnt > 0)) compact();  // resolve stragglers

  // Cross-lane tree merge over the 8 subset threads.
#pragma unroll
  for (int d = 1; d < SPL; d <<= 1) {
    u64k r[KK];
#pragma unroll
    for (int s = 0; s < KK; ++s) r[s] = __shfl_xor(kl[s], d);
    mergeTop16(kl, r);
  }

  if (h == 0) {
    float* dq = dout + (size_t)qid * KK;
    float* iq = iout + (size_t)qid * KK;
    float dv[KK], iv[KK];
#pragma unroll
    for (int o = 0; o < KK; ++o) {
      dv[o] = sqrtf(__uint_as_float((unsigned)(kl[o] >> 32)));
      iv[o] = (float)(unsigned)(kl[o] & 0xffffffffu);  // 0-based
    }
    ((float4*)dq)[0] = make_float4(dv[0], dv[1], dv[2], dv[3]);
    ((float4*)dq)[1] = make_float4(dv[4], dv[5], dv[6], dv[7]);
    ((float4*)dq)[2] = make_float4(dv[8], dv[9], dv[10], dv[11]);
    ((float4*)dq)[3] = make_float4(dv[12], dv[13], dv[14], dv[15]);
    ((float4*)iq)[0] = make_float4(iv[0], iv[1], iv[2], iv[3]);
    ((float4*)iq)[1] = make_float4(iv[4], iv[5], iv[6], iv[7]);
    ((float4*)iq)[2] = make_float4(iv[8], iv[9], iv[10], iv[11]);
    ((float4*)iq)[3] = make_float4(iv[12], iv[13], iv[14], iv[15]);
  }
}

extern "C" void kernel_launch(void* const* d_in, const int* in_sizes, int n_in,
                              void* d_out, int out_size, void* d_ws, size_t ws_size,
                              hipStream_t stream) {
  const float* ref = (const float*)d_in[0];
  const float* query = (const float*)d_in[1];
  const int B = 4, C = 3;
  int N = in_sizes[0] / (B * C);
  int M = in_sizes[1] / (B * C);
  float* dout = (float*)d_out;
  float* iout = dout + (size_t)out_size / 2;  // idx half, written as float
  int totalQ = B * M;
  int blocks = totalQ / QPB;
  knn_topk_kernel<<<blocks, TPB, 0, stream>>>(ref, query, dout, iout, N, M);
}